// Round 9
// baseline (1969.194 us; speedup 1.0000x reference)
//
#include <hip/hip_runtime.h>
#include <cstdint>

// ---- bf16 pack/unpack helpers (RNE) ----
__device__ inline unsigned int bfpack2(float a, float b) {
  unsigned int ua = __float_as_uint(a), ub = __float_as_uint(b);
  ua += 0x7FFFu + ((ua >> 16) & 1u);
  ub += 0x7FFFu + ((ub >> 16) & 1u);
  return (ua >> 16) | (ub & 0xFFFF0000u);
}
__device__ inline float bflo(unsigned int u) { return __uint_as_float(u << 16); }
__device__ inline float bfhi(unsigned int u) { return __uint_as_float(u & 0xFFFF0000u); }

// ---------------- degree histogram (dst only) ----------------
__global__ __launch_bounds__(256) void pre_kernel(const int* __restrict__ dst,
                                                  int* __restrict__ deg, int nE) {
  int e = blockIdx.x * 256 + threadIdx.x;
  if (e < nE) atomicAdd(&deg[dst[e]], 1);
}

// ---------------- scan stage A (8-pad rounding) ----------------
__global__ __launch_bounds__(256) void scanA_kernel(const int* __restrict__ deg,
                                                    int* __restrict__ rp,
                                                    int* __restrict__ part, int n) {
  __shared__ int sh[256];
  int b = blockIdx.x, t = threadIdx.x;
  int base = b * 1024 + t * 4;
  int v0 = (base + 0 < n) ? deg[base + 0] : 0;
  int v1 = (base + 1 < n) ? deg[base + 1] : 0;
  int v2 = (base + 2 < n) ? deg[base + 2] : 0;
  int v3 = (base + 3 < n) ? deg[base + 3] : 0;
  v0 = (v0 + 7) & ~7; v1 = (v1 + 7) & ~7;
  v2 = (v2 + 7) & ~7; v3 = (v3 + 7) & ~7;
  int ts = v0 + v1 + v2 + v3;
  sh[t] = ts;
  __syncthreads();
  for (int off = 1; off < 256; off <<= 1) {
    int x = (t >= off) ? sh[t - off] : 0;
    __syncthreads();
    sh[t] += x;
    __syncthreads();
  }
  int excl = sh[t] - ts;
  if (t == 255) part[b] = sh[255];
  if (base + 0 < n) rp[base + 0] = excl;
  if (base + 1 < n) rp[base + 1] = excl + v0;
  if (base + 2 < n) rp[base + 2] = excl + v0 + v1;
  if (base + 3 < n) rp[base + 3] = excl + v0 + v1 + v2;
}

__global__ void scanB_kernel(int* part, int* rp, int nb, int n) {
  if (blockIdx.x == 0 && threadIdx.x == 0) {
    int run = 0;
    for (int i = 0; i < nb; ++i) { int v = part[i]; part[i] = run; run += v; }
    rp[n] = run;
  }
}

__global__ __launch_bounds__(256) void scanC_kernel(int* __restrict__ rp,
                                                    const int* __restrict__ part,
                                                    int* __restrict__ cursor,
                                                    const int* __restrict__ deg,
                                                    float* __restrict__ dinv, int n) {
  int i = blockIdx.x * 256 + threadIdx.x;
  if (i < n) {
    int v = rp[i] + part[i >> 10];
    rp[i] = v;
    cursor[i] = v;
    dinv[i] = rsqrtf((float)deg[i] + 1.0f);
  }
}

// ---------------- place + pad fused ----------------
__global__ __launch_bounds__(256) void placepad_kernel(const int* __restrict__ src,
                                                       const int* __restrict__ dst,
                                                       const float* __restrict__ dinv,
                                                       int* __restrict__ cursor,
                                                       int2* __restrict__ swv,
                                                       const int* __restrict__ rp,
                                                       const int* __restrict__ deg,
                                                       int nE, int nN) {
  int t = blockIdx.x * 256 + threadIdx.x;
  if (t < nE) {
    int s = src[t];
    int d = dst[t];
    int p1 = atomicAdd(&cursor[d], 1);
    int2 sw; sw.x = s; sw.y = __float_as_int(dinv[s] * dinv[d]);
    swv[p1] = sw;
  } else if (t < nE + nN) {
    int i = t - nE;
    int b = rp[i] + deg[i], e = rp[i + 1];
    int2 z; z.x = i; z.y = 0;
    for (int k = b; k < e; ++k) swv[k] = z;
  }
}

// ---------------- dense GEMM: hpk2[8][N][8] = pack_bf16(act(A) @ W), slice-major ----------------
template <bool FUSED>
__global__ __launch_bounds__(256) void gemm128_kernel(const float* __restrict__ A,
                                                      const float* __restrict__ W,
                                                      const float* __restrict__ scale,
                                                      const float* __restrict__ shift,
                                                      unsigned int* __restrict__ hpk2,
                                                      int nrows) {
  extern __shared__ float lds[];
  float* Ws = lds;
  float* xs = lds + 128 * 128;
  const int t = threadIdx.x;
  for (int i = t; i < (128 * 128) / 4; i += 256)
    reinterpret_cast<float4*>(Ws)[i] = reinterpret_cast<const float4*>(W)[i];
  const int wave = t >> 6, lane = t & 63;
  const size_t sbase = (size_t)(lane >> 3) * (size_t)nrows * 8 + (lane & 7);
  for (int rb = blockIdx.x * 16; rb < nrows; rb += gridDim.x * 16) {
    int nr = min(16, nrows - rb);
    __syncthreads();
    for (int i = t; i < nr * 32; i += 256) {
      float4 v = reinterpret_cast<const float4*>(A + (size_t)rb * 128)[i];
      if (FUSED) {
        float4 sc4 = reinterpret_cast<const float4*>(scale)[i & 31];
        float4 sh4 = reinterpret_cast<const float4*>(shift)[i & 31];
        v.x = fmaxf(fmaf(v.x, sc4.x, sh4.x), 0.f);
        v.y = fmaxf(fmaf(v.y, sc4.y, sh4.y), 0.f);
        v.z = fmaxf(fmaf(v.z, sc4.z, sh4.z), 0.f);
        v.w = fmaxf(fmaf(v.w, sc4.w, sh4.w), 0.f);
      }
      reinterpret_cast<float4*>(xs)[i] = v;
    }
    __syncthreads();
    float acc[4][2] = {{0.f, 0.f}, {0.f, 0.f}, {0.f, 0.f}, {0.f, 0.f}};
    const float* xw = xs + wave * 4 * 128;
#pragma unroll 4
    for (int k = 0; k < 128; ++k) {
      float w0 = Ws[k * 128 + lane];
      float w1 = Ws[k * 128 + 64 + lane];
#pragma unroll
      for (int r = 0; r < 4; ++r) {
        float a = xw[r * 128 + k];
        acc[r][0] = fmaf(a, w0, acc[r][0]);
        acc[r][1] = fmaf(a, w1, acc[r][1]);
      }
    }
#pragma unroll
    for (int r = 0; r < 4; ++r) {
      int row = rb + wave * 4 + r;
      if (row < nrows)
        hpk2[sbase + (size_t)row * 8] = bfpack2(acc[r][0], acc[r][1]);
    }
  }
}

// ---------------- SpMM, XCD channel-sliced, TWO nodes per wave ----------------
// Pair (n, n+half) gives 4 independent gather chains per lane in the main loop.
__global__ __launch_bounds__(256) void spmm8_kernel(const unsigned int* __restrict__ hpk2,
                                                    const float* __restrict__ dinv,
                                                    const int* __restrict__ rp,
                                                    const int2* __restrict__ swv,
                                                    const float* __restrict__ bias,
                                                    float* __restrict__ outp,
                                                    float* __restrict__ bnsum,
                                                    float* __restrict__ bnsq, int nN) {
  const int lane = threadIdx.x & 63;
  const int ch = lane & 7;
  const int es = lane >> 3;
  const int slice = blockIdx.x & 7;
  const unsigned int* hs = hpk2 + (size_t)slice * (size_t)nN * 8;
  const int cb = slice * 8;
  const int wib = (int)(blockIdx.x >> 3) * 4 + (int)(threadIdx.x >> 6);
  const int nws = (int)(gridDim.x >> 3) * 4;
  const unsigned long long* swq = reinterpret_cast<const unsigned long long*>(swv);
  float b0 = bias[cb + ch], b1 = bias[64 + cb + ch];
  float s0 = 0.f, s1 = 0.f, q0 = 0.f, q1 = 0.f;
  const int half = (nN + 1) >> 1;

#define SPMM_CHUNK(J, ACC0, ACC1)                                         \
  {                                                                       \
    unsigned long long v_ = __builtin_nontemporal_load(swq + (J) + es);   \
    unsigned int pp_ = hs[(size_t)(unsigned int)v_ * 8 + ch];             \
    float ww_ = __uint_as_float((unsigned int)(v_ >> 32));                \
    ACC0 = fmaf(ww_, bflo(pp_), ACC0);                                    \
    ACC1 = fmaf(ww_, bfhi(pp_), ACC1);                                    \
  }

  for (int p = wib; p < half; p += nws) {
    const int n0 = p;
    const int n1 = p + half;
    const bool has1 = n1 < nN;
    int j0 = rp[n0];
    const int end0 = rp[n0 + 1];
    int j1 = 0, end1 = 0;
    if (has1) { j1 = rp[n1]; end1 = rp[n1 + 1]; }
    float a00 = 0.f, a01 = 0.f, b00 = 0.f, b01 = 0.f;
    float a10 = 0.f, a11 = 0.f, b10 = 0.f, b11 = 0.f;
    while (j0 + 8 < end0 && j1 + 8 < end1) {
      SPMM_CHUNK(j0, a00, a01);
      SPMM_CHUNK(j0 + 8, b00, b01);
      SPMM_CHUNK(j1, a10, a11);
      SPMM_CHUNK(j1 + 8, b10, b11);
      j0 += 16; j1 += 16;
    }
    while (j0 + 8 < end0) {
      SPMM_CHUNK(j0, a00, a01);
      SPMM_CHUNK(j0 + 8, b00, b01);
      j0 += 16;
    }
    if (j0 < end0) SPMM_CHUNK(j0, a00, a01);
    while (j1 + 8 < end1) {
      SPMM_CHUNK(j1, a10, a11);
      SPMM_CHUNK(j1 + 8, b10, b11);
      j1 += 16;
    }
    if (j1 < end1) SPMM_CHUNK(j1, a10, a11);

    a00 += b00; a01 += b01;
    a10 += b10; a11 += b11;
    a00 += __shfl_xor(a00, 8);  a01 += __shfl_xor(a01, 8);
    a10 += __shfl_xor(a10, 8);  a11 += __shfl_xor(a11, 8);
    a00 += __shfl_xor(a00, 16); a01 += __shfl_xor(a01, 16);
    a10 += __shfl_xor(a10, 16); a11 += __shfl_xor(a11, 16);
    a00 += __shfl_xor(a00, 32); a01 += __shfl_xor(a01, 32);
    a10 += __shfl_xor(a10, 32); a11 += __shfl_xor(a11, 32);
    if (es == 0) {
      {
        float dn = dinv[n0];
        float sw = dn * dn;
        unsigned int pn = hs[(size_t)n0 * 8 + ch];
        float o0 = fmaf(bflo(pn), sw, a00) + b0;
        float o1 = fmaf(bfhi(pn), sw, a01) + b1;
        __builtin_nontemporal_store(o0, &outp[(size_t)n0 * 128 + cb + ch]);
        __builtin_nontemporal_store(o1, &outp[(size_t)n0 * 128 + 64 + cb + ch]);
        s0 += o0; s1 += o1;
        q0 = fmaf(o0, o0, q0); q1 = fmaf(o1, o1, q1);
      }
      if (has1) {
        float dn = dinv[n1];
        float sw = dn * dn;
        unsigned int pn = hs[(size_t)n1 * 8 + ch];
        float o0 = fmaf(bflo(pn), sw, a10) + b0;
        float o1 = fmaf(bfhi(pn), sw, a11) + b1;
        __builtin_nontemporal_store(o0, &outp[(size_t)n1 * 128 + cb + ch]);
        __builtin_nontemporal_store(o1, &outp[(size_t)n1 * 128 + 64 + cb + ch]);
        s0 += o0; s1 += o1;
        q0 = fmaf(o0, o0, q0); q1 = fmaf(o1, o1, q1);
      }
    }
  }
#undef SPMM_CHUNK
  if (es == 0) {
    atomicAdd(&bnsum[cb + ch], s0);
    atomicAdd(&bnsum[64 + cb + ch], s1);
    atomicAdd(&bnsq[cb + ch], q0);
    atomicAdd(&bnsq[64 + cb + ch], q1);
  }
}

// ---------------- BN finalize ----------------
__global__ void bnfin_kernel(const float* __restrict__ sum, const float* __restrict__ sq,
                             const float* __restrict__ gamma, const float* __restrict__ beta,
                             float* __restrict__ scale, float* __restrict__ shift,
                             float invN) {
  int c = threadIdx.x;
  float mu = sum[c] * invN;
  float var = sq[c] * invN - mu * mu;
  float sc = gamma[c] * rsqrtf(var + 1e-5f);
  scale[c] = sc;
  shift[c] = beta[c] - mu * sc;
}

// ---------------- graph mean pool, fused BN+ReLU ----------------
__global__ __launch_bounds__(256) void pool_kernel(const float* __restrict__ h,
                                                   const int* __restrict__ batch,
                                                   const float* __restrict__ scale,
                                                   const float* __restrict__ shift,
                                                   float* __restrict__ gsum,
                                                   float* __restrict__ gcnt,
                                                   int nN, int chunk) {
  const int lane = threadIdx.x & 63;
  const int wid = (blockIdx.x * blockDim.x + threadIdx.x) >> 6;
  int beg = wid * chunk;
  if (beg >= nN) return;
  int end = min(nN, beg + chunk);
  const int c2 = 2 * lane;
  float2 sc2 = *reinterpret_cast<const float2*>(scale + c2);
  float2 sh2 = *reinterpret_cast<const float2*>(shift + c2);
  int cur = -1;
  float a0 = 0.f, a1 = 0.f, cnt = 0.f;
  for (int n = beg; n < end; ++n) {
    int g = batch[n];
    if (g != cur) {
      if (cur >= 0) {
        atomicAdd(&gsum[cur * 128 + c2], a0);
        atomicAdd(&gsum[cur * 128 + c2 + 1], a1);
        if (lane == 0) atomicAdd(&gcnt[cur], cnt);
      }
      cur = g; a0 = 0.f; a1 = 0.f; cnt = 0.f;
    }
    float2 v = *reinterpret_cast<const float2*>(h + (size_t)n * 128 + c2);
    a0 += fmaxf(fmaf(v.x, sc2.x, sh2.x), 0.f);
    a1 += fmaxf(fmaf(v.y, sc2.y, sh2.y), 0.f);
    cnt += 1.f;
  }
  if (cur >= 0) {
    atomicAdd(&gsum[cur * 128 + c2], a0);
    atomicAdd(&gsum[cur * 128 + c2 + 1], a1);
    if (lane == 0) atomicAdd(&gcnt[cur], cnt);
  }
}

// ---------------- edge MLP, SEQUENTIAL ea stream + LDS per-graph accumulate ----------------
// ea read in memory order (coalesced 64B/edge). Graph id via batch[src[e]] (L2-resident
// 400KB gather, off the FMA critical path). LDS table [256][128] fp32 atomics (lanes hit
// distinct banks). Per-block partials written to pb[b] (no global atomics), reduced in final.
__global__ __launch_bounds__(1024) void edge3_kernel(const float* __restrict__ ea,
                                                     const int* __restrict__ src,
                                                     const int* __restrict__ batch,
                                                     const float* __restrict__ We1,
                                                     const float* __restrict__ be1,
                                                     float* __restrict__ pb,
                                                     int nE, int chunk) {
  extern __shared__ float es[];  // 256*128 + 256 floats
  float* cs = es + 256 * 128;
  const int t = threadIdx.x;
  for (int i = t; i < 256 * 128 + 256; i += 1024) es[i] = 0.f;
  const int lane = t & 63;
  float w0[16], w1[16];
#pragma unroll
  for (int k = 0; k < 16; ++k) {
    w0[k] = We1[k * 128 + lane];
    w1[k] = We1[k * 128 + 64 + lane];
  }
  float b0 = be1[lane], b1 = be1[64 + lane];
  __syncthreads();
  const int wid = (blockIdx.x * 1024 + t) >> 6;
  int beg = wid * chunk;
  int end = min(nE, beg + chunk);
  if (beg < end) {
    int e = beg;
    for (; e + 1 < end; e += 2) {
      int s0 = src[e], s1 = src[e + 1];
      int g0 = batch[s0], g1 = batch[s1];
      const float4* p0 = reinterpret_cast<const float4*>(ea + (size_t)e * 16);
      float4 A0 = p0[0], A1 = p0[1], A2 = p0[2], A3 = p0[3];
      float4 B0 = p0[4], B1 = p0[5], B2 = p0[6], B3 = p0[7];
      float av[16] = {A0.x, A0.y, A0.z, A0.w, A1.x, A1.y, A1.z, A1.w,
                      A2.x, A2.y, A2.z, A2.w, A3.x, A3.y, A3.z, A3.w};
      float bv[16] = {B0.x, B0.y, B0.z, B0.w, B1.x, B1.y, B1.z, B1.w,
                      B2.x, B2.y, B2.z, B2.w, B3.x, B3.y, B3.z, B3.w};
      float u0 = b0, u1 = b1, x0 = b0, x1 = b1;
#pragma unroll
      for (int k = 0; k < 16; ++k) {
        u0 = fmaf(av[k], w0[k], u0);
        u1 = fmaf(av[k], w1[k], u1);
        x0 = fmaf(bv[k], w0[k], x0);
        x1 = fmaf(bv[k], w1[k], x1);
      }
      u0 = fmaxf(u0, 0.f); u1 = fmaxf(u1, 0.f);
      x0 = fmaxf(x0, 0.f); x1 = fmaxf(x1, 0.f);
      atomicAdd(&es[g0 * 128 + lane], u0);
      atomicAdd(&es[g0 * 128 + 64 + lane], u1);
      atomicAdd(&es[g1 * 128 + lane], x0);
      atomicAdd(&es[g1 * 128 + 64 + lane], x1);
      if (lane == 0) {
        atomicAdd(&cs[g0], 1.f);
        atomicAdd(&cs[g1], 1.f);
      }
    }
    if (e < end) {
      int s0 = src[e];
      int g0 = batch[s0];
      const float4* p0 = reinterpret_cast<const float4*>(ea + (size_t)e * 16);
      float4 A0 = p0[0], A1 = p0[1], A2 = p0[2], A3 = p0[3];
      float av[16] = {A0.x, A0.y, A0.z, A0.w, A1.x, A1.y, A1.z, A1.w,
                      A2.x, A2.y, A2.z, A2.w, A3.x, A3.y, A3.z, A3.w};
      float u0 = b0, u1 = b1;
#pragma unroll
      for (int k = 0; k < 16; ++k) {
        u0 = fmaf(av[k], w0[k], u0);
        u1 = fmaf(av[k], w1[k], u1);
      }
      u0 = fmaxf(u0, 0.f); u1 = fmaxf(u1, 0.f);
      atomicAdd(&es[g0 * 128 + lane], u0);
      atomicAdd(&es[g0 * 128 + 64 + lane], u1);
      if (lane == 0) atomicAdd(&cs[g0], 1.f);
    }
  }
  __syncthreads();
  float* myp = pb + (size_t)blockIdx.x * 33024;
  for (int i = t; i < 256 * 128 + 256; i += 1024) myp[i] = es[i];
}

// ---------------- final: graph_repr + edge_repr (reduces pb partials) ----------------
__global__ __launch_bounds__(128) void final_kernel(const float* __restrict__ gsum,
                                                    const float* __restrict__ gcnt,
                                                    const float* __restrict__ pb,
                                                    const float* __restrict__ We2,
                                                    const float* __restrict__ be2,
                                                    float* __restrict__ out) {
  __shared__ float row[128];
  int g = blockIdx.x, c = threadIdx.x;
  float acc_e = 0.f, cnt_e = 0.f;
  for (int b = 0; b < 256; ++b) {
    const float* base = pb + (size_t)b * 33024;
    acc_e += base[g * 128 + c];
    cnt_e += base[256 * 128 + g];
  }
  row[c] = acc_e;
  __syncthreads();
  float acc = 0.f;
#pragma unroll 4
  for (int k = 0; k < 128; ++k) acc = fmaf(row[k], We2[k * 128 + c], acc);
  float er = (cnt_e > 0.f) ? (acc / cnt_e + be2[c]) : 0.f;
  float gr = gsum[g * 128 + c] / fmaxf(gcnt[g], 1.f);
  out[g * 128 + c] = gr + er;
}

extern "C" void kernel_launch(void* const* d_in, const int* in_sizes, int n_in,
                              void* d_out, int out_size, void* d_ws, size_t ws_size,
                              hipStream_t stream) {
  const float* x    = (const float*)d_in[0];
  const int*   ei   = (const int*)d_in[1];
  const float* ea   = (const float*)d_in[2];
  const int*   bidx = (const int*)d_in[3];
  const float* Wg1  = (const float*)d_in[4];
  const float* bg1  = (const float*)d_in[5];
  const float* gm1  = (const float*)d_in[6];
  const float* bt1  = (const float*)d_in[7];
  const float* Wg2  = (const float*)d_in[8];
  const float* bg2  = (const float*)d_in[9];
  const float* gm2  = (const float*)d_in[10];
  const float* bt2  = (const float*)d_in[11];
  const float* We1  = (const float*)d_in[12];
  const float* be1  = (const float*)d_in[13];
  const float* We2  = (const float*)d_in[14];
  const float* be2  = (const float*)d_in[15];
  float* out = (float*)d_out;

  const int N = in_sizes[3];
  const int E = in_sizes[1] / 2;
  const int G = out_size / 128;
  const int* srcp = ei;
  const int* dstp = ei + E;
  const int Epad = E + 8 * N;

  char* w = (char*)d_ws;
  auto alloc = [&](size_t b) {
    char* p = w;
    w += (b + 15) & ~(size_t)15;
    return p;
  };
  float* bufB    = (float*)alloc((size_t)N * 128 * 4);            // fp32 spmm output
  unsigned int* hpk2 = (unsigned int*)alloc((size_t)N * 64 * 4);  // packed bf16 h, slice-major
  int2*  swv     = (int2*)alloc((size_t)Epad * 8);                // interleaved {src, wgt}
  int*   rp      = (int*)alloc((size_t)(N + 1) * 4);
  int*   cursor  = (int*)alloc((size_t)N * 4);
  float* dinv    = (float*)alloc((size_t)N * 4);
  char* zbase = w;
  int*   deg  = (int*)alloc((size_t)N * 4);
  float* bs1  = (float*)alloc(512);
  float* bq1  = (float*)alloc(512);
  float* bs2  = (float*)alloc(512);
  float* bq2  = (float*)alloc(512);
  float* gsum = (float*)alloc((size_t)G * 128 * 4);
  float* gcnt = (float*)alloc((size_t)G * 4);
  int*   part = (int*)alloc(4096);
  size_t zbytes = (size_t)(w - zbase);
  float* sc1 = (float*)alloc(512);
  float* sh1 = (float*)alloc(512);
  float* sc2 = (float*)alloc(512);
  float* sh2 = (float*)alloc(512);

  // pb (256 blocks x (256*128 + 256) floats = 33.8 MB) aliases hpk2+swv (39.4 MB),
  // which are dead after spmm2. edge3 runs after spmm2.
  float* pb = (float*)hpk2;

  hipMemsetAsync(zbase, 0, zbytes, stream);

  (void)hipFuncSetAttribute((const void*)gemm128_kernel<false>,
                            hipFuncAttributeMaxDynamicSharedMemorySize, 73728);
  (void)hipFuncSetAttribute((const void*)gemm128_kernel<true>,
                            hipFuncAttributeMaxDynamicSharedMemorySize, 73728);
  (void)hipFuncSetAttribute((const void*)edge3_kernel,
                            hipFuncAttributeMaxDynamicSharedMemorySize, 132096);

  // ---- prep ----
  pre_kernel<<<(E + 255) / 256, 256, 0, stream>>>(dstp, deg, E);
  int nb = (N + 1023) / 1024;
  scanA_kernel<<<nb, 256, 0, stream>>>(deg, rp, part, N);
  scanB_kernel<<<1, 1, 0, stream>>>(part, rp, nb, N);
  scanC_kernel<<<(N + 255) / 256, 256, 0, stream>>>(rp, part, cursor, deg, dinv, N);
  placepad_kernel<<<(E + N + 255) / 256, 256, 0, stream>>>(srcp, dstp, dinv, cursor,
                                                           swv, rp, deg, E, N);

  // layer 1
  gemm128_kernel<false><<<512, 256, 73728, stream>>>(x, Wg1, nullptr, nullptr, hpk2, N);
  spmm8_kernel<<<2048, 256, 0, stream>>>(hpk2, dinv, rp, swv, bg1, bufB, bs1, bq1, N);
  bnfin_kernel<<<1, 128, 0, stream>>>(bs1, bq1, gm1, bt1, sc1, sh1, 1.0f / (float)N);

  // layer 2 (BN1+ReLU fused into GEMM2's A staging)
  gemm128_kernel<true><<<512, 256, 73728, stream>>>(bufB, Wg2, sc1, sh1, hpk2, N);
  spmm8_kernel<<<2048, 256, 0, stream>>>(hpk2, dinv, rp, swv, bg2, bufB, bs2, bq2, N);
  bnfin_kernel<<<1, 128, 0, stream>>>(bs2, bq2, gm2, bt2, sc2, sh2, 1.0f / (float)N);

  // pooling (BN2+ReLU fused)
  int nwp = (2048 * 256) / 64;
  int chunkN = (N + nwp - 1) / nwp;
  pool_kernel<<<2048, 256, 0, stream>>>(bufB, bidx, sc2, sh2, gsum, gcnt, N, chunkN);

  // edge path (sequential stream; hpk2/swv now dead -> pb aliases them)
  int nweg = 256 * 16;  // 256 blocks x 16 waves
  int chunkE = (E + nweg - 1) / nweg;
  edge3_kernel<<<256, 1024, 132096, stream>>>(ea, srcp, bidx, We1, be1, pb, E, chunkE);

  final_kernel<<<G, 128, 0, stream>>>(gsum, gcnt, pb, We2, be2, out);
}

// Round 10
// 1497.874 us; speedup vs baseline: 1.3147x; 1.3147x over previous
//
#include <hip/hip_runtime.h>
#include <cstdint>

// ---- bf16 pack/unpack helpers (RNE) ----
__device__ inline unsigned int bfpack2(float a, float b) {
  unsigned int ua = __float_as_uint(a), ub = __float_as_uint(b);
  ua += 0x7FFFu + ((ua >> 16) & 1u);
  ub += 0x7FFFu + ((ub >> 16) & 1u);
  return (ua >> 16) | (ub & 0xFFFF0000u);
}
__device__ inline float bflo(unsigned int u) { return __uint_as_float(u << 16); }
__device__ inline float bfhi(unsigned int u) { return __uint_as_float(u & 0xFFFF0000u); }

// ---------------- degree histograms ----------------
__global__ __launch_bounds__(256) void pre_kernel(const int* __restrict__ src,
                                                  const int* __restrict__ dst,
                                                  int* __restrict__ deg,
                                                  int* __restrict__ deg2, int nE) {
  int e = blockIdx.x * 256 + threadIdx.x;
  if (e < nE) {
    atomicAdd(&deg[dst[e]], 1);
    atomicAdd(&deg2[src[e]], 1);
  }
}

// ---------------- scan stage A (dual; deg gets 8-pad rounding) ----------------
__global__ __launch_bounds__(256) void scanA_kernel(const int* __restrict__ deg,
                                                    const int* __restrict__ deg2,
                                                    int* __restrict__ rp,
                                                    int* __restrict__ rp2,
                                                    int* __restrict__ part,
                                                    int* __restrict__ part2,
                                                    int n, int nb) {
  __shared__ int sh[256];
  int b = blockIdx.x, t = threadIdx.x;
  const int* d = (b < nb) ? deg : deg2;
  int* r = (b < nb) ? rp : rp2;
  int* p = (b < nb) ? part : part2;
  int pad = (b < nb) ? 1 : 0;
  int bb = (b < nb) ? b : b - nb;
  int base = bb * 1024 + t * 4;
  int v0 = (base + 0 < n) ? d[base + 0] : 0;
  int v1 = (base + 1 < n) ? d[base + 1] : 0;
  int v2 = (base + 2 < n) ? d[base + 2] : 0;
  int v3 = (base + 3 < n) ? d[base + 3] : 0;
  if (pad) {
    v0 = (v0 + 7) & ~7; v1 = (v1 + 7) & ~7;
    v2 = (v2 + 7) & ~7; v3 = (v3 + 7) & ~7;
  }
  int ts = v0 + v1 + v2 + v3;
  sh[t] = ts;
  __syncthreads();
  for (int off = 1; off < 256; off <<= 1) {
    int x = (t >= off) ? sh[t - off] : 0;
    __syncthreads();
    sh[t] += x;
    __syncthreads();
  }
  int excl = sh[t] - ts;
  if (t == 255) p[bb] = sh[255];
  if (base + 0 < n) r[base + 0] = excl;
  if (base + 1 < n) r[base + 1] = excl + v0;
  if (base + 2 < n) r[base + 2] = excl + v0 + v1;
  if (base + 3 < n) r[base + 3] = excl + v0 + v1 + v2;
}

__global__ void scanB_kernel(int* part, int* part2, int* rp, int* rp2, int nb, int n) {
  if (threadIdx.x == 0) {
    int* p = (blockIdx.x == 0) ? part : part2;
    int* r = (blockIdx.x == 0) ? rp : rp2;
    int run = 0;
    for (int i = 0; i < nb; ++i) { int v = p[i]; p[i] = run; run += v; }
    r[n] = run;
  }
}

__global__ __launch_bounds__(256) void scanC_kernel(int* __restrict__ rp,
                                                    int* __restrict__ rp2,
                                                    const int* __restrict__ part,
                                                    const int* __restrict__ part2,
                                                    int* __restrict__ cursor,
                                                    int* __restrict__ cursor2,
                                                    const int* __restrict__ deg,
                                                    float* __restrict__ dinv, int n) {
  int i = blockIdx.x * 256 + threadIdx.x;
  if (i < n) {
    int v = rp[i] + part[i >> 10];
    rp[i] = v;
    cursor[i] = v;
    dinv[i] = rsqrtf((float)deg[i] + 1.0f);
  } else if (i < 2 * n) {
    int j = i - n;
    int v = rp2[j] + part2[j >> 10];
    rp2[j] = v;
    cursor2[j] = v;
  }
}

// ---------------- place + pad fused ----------------
__global__ __launch_bounds__(256) void placepad_kernel(const int* __restrict__ src,
                                                       const int* __restrict__ dst,
                                                       const int* __restrict__ batch,
                                                       const float* __restrict__ dinv,
                                                       int* __restrict__ cursor,
                                                       int* __restrict__ cursor2,
                                                       int2* __restrict__ swv,
                                                       unsigned int* __restrict__ epk,
                                                       const int* __restrict__ rp,
                                                       const int* __restrict__ deg,
                                                       int nE, int nN) {
  int t = blockIdx.x * 256 + threadIdx.x;
  if (t < nE) {
    int s = src[t];
    int d = dst[t];
    int p1 = atomicAdd(&cursor[d], 1);
    int2 sw; sw.x = s; sw.y = __float_as_int(dinv[s] * dinv[d]);
    swv[p1] = sw;
    int g = batch[s];
    int p2 = atomicAdd(&cursor2[s], 1);
    epk[p2] = ((unsigned int)g << 21) | (unsigned int)t;
  } else if (t < nE + nN) {
    int i = t - nE;
    int b = rp[i] + deg[i], e = rp[i + 1];
    int2 z; z.x = i; z.y = 0;
    for (int k = b; k < e; ++k) swv[k] = z;
  }
}

// ---------------- dense GEMM: hpk2[8][N][8] = pack_bf16(act(A) @ W), slice-major ----------------
template <bool FUSED>
__global__ __launch_bounds__(256) void gemm128_kernel(const float* __restrict__ A,
                                                      const float* __restrict__ W,
                                                      const float* __restrict__ scale,
                                                      const float* __restrict__ shift,
                                                      unsigned int* __restrict__ hpk2,
                                                      int nrows) {
  extern __shared__ float lds[];
  float* Ws = lds;
  float* xs = lds + 128 * 128;
  const int t = threadIdx.x;
  for (int i = t; i < (128 * 128) / 4; i += 256)
    reinterpret_cast<float4*>(Ws)[i] = reinterpret_cast<const float4*>(W)[i];
  const int wave = t >> 6, lane = t & 63;
  const size_t sbase = (size_t)(lane >> 3) * (size_t)nrows * 8 + (lane & 7);
  for (int rb = blockIdx.x * 16; rb < nrows; rb += gridDim.x * 16) {
    int nr = min(16, nrows - rb);
    __syncthreads();
    for (int i = t; i < nr * 32; i += 256) {
      float4 v = reinterpret_cast<const float4*>(A + (size_t)rb * 128)[i];
      if (FUSED) {
        float4 sc4 = reinterpret_cast<const float4*>(scale)[i & 31];
        float4 sh4 = reinterpret_cast<const float4*>(shift)[i & 31];
        v.x = fmaxf(fmaf(v.x, sc4.x, sh4.x), 0.f);
        v.y = fmaxf(fmaf(v.y, sc4.y, sh4.y), 0.f);
        v.z = fmaxf(fmaf(v.z, sc4.z, sh4.z), 0.f);
        v.w = fmaxf(fmaf(v.w, sc4.w, sh4.w), 0.f);
      }
      reinterpret_cast<float4*>(xs)[i] = v;
    }
    __syncthreads();
    float acc[4][2] = {{0.f, 0.f}, {0.f, 0.f}, {0.f, 0.f}, {0.f, 0.f}};
    const float* xw = xs + wave * 4 * 128;
#pragma unroll 4
    for (int k = 0; k < 128; ++k) {
      float w0 = Ws[k * 128 + lane];
      float w1 = Ws[k * 128 + 64 + lane];
#pragma unroll
      for (int r = 0; r < 4; ++r) {
        float a = xw[r * 128 + k];
        acc[r][0] = fmaf(a, w0, acc[r][0]);
        acc[r][1] = fmaf(a, w1, acc[r][1]);
      }
    }
#pragma unroll
    for (int r = 0; r < 4; ++r) {
      int row = rb + wave * 4 + r;
      if (row < nrows)
        hpk2[sbase + (size_t)row * 8] = bfpack2(acc[r][0], acc[r][1]);
    }
  }
}

// ---------------- SpMM, XCD channel-sliced, TWO nodes per wave ----------------
__global__ __launch_bounds__(256) void spmm8_kernel(const unsigned int* __restrict__ hpk2,
                                                    const float* __restrict__ dinv,
                                                    const int* __restrict__ rp,
                                                    const int2* __restrict__ swv,
                                                    const float* __restrict__ bias,
                                                    float* __restrict__ outp,
                                                    float* __restrict__ bnsum,
                                                    float* __restrict__ bnsq, int nN) {
  const int lane = threadIdx.x & 63;
  const int ch = lane & 7;
  const int es = lane >> 3;
  const int slice = blockIdx.x & 7;
  const unsigned int* hs = hpk2 + (size_t)slice * (size_t)nN * 8;
  const int cb = slice * 8;
  const int wib = (int)(blockIdx.x >> 3) * 4 + (int)(threadIdx.x >> 6);
  const int nws = (int)(gridDim.x >> 3) * 4;
  const unsigned long long* swq = reinterpret_cast<const unsigned long long*>(swv);
  float b0 = bias[cb + ch], b1 = bias[64 + cb + ch];
  float s0 = 0.f, s1 = 0.f, q0 = 0.f, q1 = 0.f;
  const int half = (nN + 1) >> 1;

#define SPMM_CHUNK(J, ACC0, ACC1)                                         \
  {                                                                       \
    unsigned long long v_ = __builtin_nontemporal_load(swq + (J) + es);   \
    unsigned int pp_ = hs[(size_t)(unsigned int)v_ * 8 + ch];             \
    float ww_ = __uint_as_float((unsigned int)(v_ >> 32));                \
    ACC0 = fmaf(ww_, bflo(pp_), ACC0);                                    \
    ACC1 = fmaf(ww_, bfhi(pp_), ACC1);                                    \
  }

  for (int p = wib; p < half; p += nws) {
    const int n0 = p;
    const int n1 = p + half;
    const bool has1 = n1 < nN;
    int j0 = rp[n0];
    const int end0 = rp[n0 + 1];
    int j1 = 0, end1 = 0;
    if (has1) { j1 = rp[n1]; end1 = rp[n1 + 1]; }
    float a00 = 0.f, a01 = 0.f, b00 = 0.f, b01 = 0.f;
    float a10 = 0.f, a11 = 0.f, b10 = 0.f, b11 = 0.f;
    while (j0 + 8 < end0 && j1 + 8 < end1) {
      SPMM_CHUNK(j0, a00, a01);
      SPMM_CHUNK(j0 + 8, b00, b01);
      SPMM_CHUNK(j1, a10, a11);
      SPMM_CHUNK(j1 + 8, b10, b11);
      j0 += 16; j1 += 16;
    }
    while (j0 + 8 < end0) {
      SPMM_CHUNK(j0, a00, a01);
      SPMM_CHUNK(j0 + 8, b00, b01);
      j0 += 16;
    }
    if (j0 < end0) SPMM_CHUNK(j0, a00, a01);
    while (j1 + 8 < end1) {
      SPMM_CHUNK(j1, a10, a11);
      SPMM_CHUNK(j1 + 8, b10, b11);
      j1 += 16;
    }
    if (j1 < end1) SPMM_CHUNK(j1, a10, a11);

    a00 += b00; a01 += b01;
    a10 += b10; a11 += b11;
    a00 += __shfl_xor(a00, 8);  a01 += __shfl_xor(a01, 8);
    a10 += __shfl_xor(a10, 8);  a11 += __shfl_xor(a11, 8);
    a00 += __shfl_xor(a00, 16); a01 += __shfl_xor(a01, 16);
    a10 += __shfl_xor(a10, 16); a11 += __shfl_xor(a11, 16);
    a00 += __shfl_xor(a00, 32); a01 += __shfl_xor(a01, 32);
    a10 += __shfl_xor(a10, 32); a11 += __shfl_xor(a11, 32);
    if (es == 0) {
      {
        float dn = dinv[n0];
        float sw = dn * dn;
        unsigned int pn = hs[(size_t)n0 * 8 + ch];
        float o0 = fmaf(bflo(pn), sw, a00) + b0;
        float o1 = fmaf(bfhi(pn), sw, a01) + b1;
        __builtin_nontemporal_store(o0, &outp[(size_t)n0 * 128 + cb + ch]);
        __builtin_nontemporal_store(o1, &outp[(size_t)n0 * 128 + 64 + cb + ch]);
        s0 += o0; s1 += o1;
        q0 = fmaf(o0, o0, q0); q1 = fmaf(o1, o1, q1);
      }
      if (has1) {
        float dn = dinv[n1];
        float sw = dn * dn;
        unsigned int pn = hs[(size_t)n1 * 8 + ch];
        float o0 = fmaf(bflo(pn), sw, a10) + b0;
        float o1 = fmaf(bfhi(pn), sw, a11) + b1;
        __builtin_nontemporal_store(o0, &outp[(size_t)n1 * 128 + cb + ch]);
        __builtin_nontemporal_store(o1, &outp[(size_t)n1 * 128 + 64 + cb + ch]);
        s0 += o0; s1 += o1;
        q0 = fmaf(o0, o0, q0); q1 = fmaf(o1, o1, q1);
      }
    }
  }
#undef SPMM_CHUNK
  if (es == 0) {
    atomicAdd(&bnsum[cb + ch], s0);
    atomicAdd(&bnsum[64 + cb + ch], s1);
    atomicAdd(&bnsq[cb + ch], q0);
    atomicAdd(&bnsq[64 + cb + ch], q1);
  }
}

// ---------------- BN finalize ----------------
__global__ void bnfin_kernel(const float* __restrict__ sum, const float* __restrict__ sq,
                             const float* __restrict__ gamma, const float* __restrict__ beta,
                             float* __restrict__ scale, float* __restrict__ shift,
                             float invN) {
  int c = threadIdx.x;
  float mu = sum[c] * invN;
  float var = sq[c] * invN - mu * mu;
  float sc = gamma[c] * rsqrtf(var + 1e-5f);
  scale[c] = sc;
  shift[c] = beta[c] - mu * sc;
}

// ---------------- graph mean pool, fused BN+ReLU ----------------
__global__ __launch_bounds__(256) void pool_kernel(const float* __restrict__ h,
                                                   const int* __restrict__ batch,
                                                   const float* __restrict__ scale,
                                                   const float* __restrict__ shift,
                                                   float* __restrict__ gsum,
                                                   float* __restrict__ gcnt,
                                                   int nN, int chunk) {
  const int lane = threadIdx.x & 63;
  const int wid = (blockIdx.x * blockDim.x + threadIdx.x) >> 6;
  int beg = wid * chunk;
  if (beg >= nN) return;
  int end = min(nN, beg + chunk);
  const int c2 = 2 * lane;
  float2 sc2 = *reinterpret_cast<const float2*>(scale + c2);
  float2 sh2 = *reinterpret_cast<const float2*>(shift + c2);
  int cur = -1;
  float a0 = 0.f, a1 = 0.f, cnt = 0.f;
  for (int n = beg; n < end; ++n) {
    int g = batch[n];
    if (g != cur) {
      if (cur >= 0) {
        atomicAdd(&gsum[cur * 128 + c2], a0);
        atomicAdd(&gsum[cur * 128 + c2 + 1], a1);
        if (lane == 0) atomicAdd(&gcnt[cur], cnt);
      }
      cur = g; a0 = 0.f; a1 = 0.f; cnt = 0.f;
    }
    float2 v = *reinterpret_cast<const float2*>(h + (size_t)n * 128 + c2);
    a0 += fmaxf(fmaf(v.x, sc2.x, sh2.x), 0.f);
    a1 += fmaxf(fmaf(v.y, sc2.y, sh2.y), 0.f);
    cnt += 1.f;
  }
  if (cur >= 0) {
    atomicAdd(&gsum[cur * 128 + c2], a0);
    atomicAdd(&gsum[cur * 128 + c2 + 1], a1);
    if (lane == 0) atomicAdd(&gcnt[cur], cnt);
  }
}

// ---------------- edge MLP: epk-ordered (graph-sorted), 4 rows in flight ----------------
#define MLP16(R0, R1, R2, R3, U0, U1)                          \
  do {                                                         \
    U0 = b0; U1 = b1;                                          \
    U0 = fmaf(R0.x, w0[0], U0);  U1 = fmaf(R0.x, w1[0], U1);   \
    U0 = fmaf(R0.y, w0[1], U0);  U1 = fmaf(R0.y, w1[1], U1);   \
    U0 = fmaf(R0.z, w0[2], U0);  U1 = fmaf(R0.z, w1[2], U1);   \
    U0 = fmaf(R0.w, w0[3], U0);  U1 = fmaf(R0.w, w1[3], U1);   \
    U0 = fmaf(R1.x, w0[4], U0);  U1 = fmaf(R1.x, w1[4], U1);   \
    U0 = fmaf(R1.y, w0[5], U0);  U1 = fmaf(R1.y, w1[5], U1);   \
    U0 = fmaf(R1.z, w0[6], U0);  U1 = fmaf(R1.z, w1[6], U1);   \
    U0 = fmaf(R1.w, w0[7], U0);  U1 = fmaf(R1.w, w1[7], U1);   \
    U0 = fmaf(R2.x, w0[8], U0);  U1 = fmaf(R2.x, w1[8], U1);   \
    U0 = fmaf(R2.y, w0[9], U0);  U1 = fmaf(R2.y, w1[9], U1);   \
    U0 = fmaf(R2.z, w0[10], U0); U1 = fmaf(R2.z, w1[10], U1);  \
    U0 = fmaf(R2.w, w0[11], U0); U1 = fmaf(R2.w, w1[11], U1);  \
    U0 = fmaf(R3.x, w0[12], U0); U1 = fmaf(R3.x, w1[12], U1);  \
    U0 = fmaf(R3.y, w0[13], U0); U1 = fmaf(R3.y, w1[13], U1);  \
    U0 = fmaf(R3.z, w0[14], U0); U1 = fmaf(R3.z, w1[14], U1);  \
    U0 = fmaf(R3.w, w0[15], U0); U1 = fmaf(R3.w, w1[15], U1);  \
  } while (0)

#define EFLUSH()                                               \
  do {                                                         \
    if (cur >= 0) {                                            \
      atomicAdd(&esum[cur * 128 + lane], a0);                  \
      atomicAdd(&esum[cur * 128 + 64 + lane], a1);             \
      if (lane == 0) atomicAdd(&ecnt[cur], cnt);               \
    }                                                          \
  } while (0)

#define ONE_EDGE(K)                                            \
  do {                                                         \
    int g_ = (int)((K) >> 21);                                 \
    if (g_ != cur) { EFLUSH(); cur = g_; a0 = 0.f; a1 = 0.f; cnt = 0.f; } \
    int e_ = (int)((K) & 0x1FFFFFu);                           \
    const float4* p_ = reinterpret_cast<const float4*>(ea + (size_t)e_ * 16); \
    float4 R0 = p_[0], R1 = p_[1], R2 = p_[2], R3 = p_[3];     \
    float u_, v_;                                              \
    MLP16(R0, R1, R2, R3, u_, v_);                             \
    a0 += fmaxf(u_, 0.f);                                      \
    a1 += fmaxf(v_, 0.f);                                      \
    cnt += 1.f;                                                \
  } while (0)

__global__ __launch_bounds__(256, 4) void edge4_kernel(const float* __restrict__ ea,
                                                       const unsigned int* __restrict__ epk,
                                                       const float* __restrict__ We1,
                                                       const float* __restrict__ be1,
                                                       float* __restrict__ esum,
                                                       float* __restrict__ ecnt,
                                                       int nE, int chunk) {
  const int lane = threadIdx.x & 63;
  const int wid = (blockIdx.x * 256 + threadIdx.x) >> 6;
  int beg = wid * chunk;
  if (beg >= nE) return;
  int end = min(nE, beg + chunk);
  float w0[16], w1[16];
#pragma unroll
  for (int k = 0; k < 16; ++k) {
    w0[k] = We1[k * 128 + lane];
    w1[k] = We1[k * 128 + 64 + lane];
  }
  float b0 = be1[lane], b1 = be1[64 + lane];
  int cur = -1;
  float a0 = 0.f, a1 = 0.f, cnt = 0.f;
  int j = beg;
  while (j + 4 <= end) {
    unsigned int k0 = epk[j], k1 = epk[j + 1], k2 = epk[j + 2], k3 = epk[j + 3];
    if ((((k0 ^ k1) | (k0 ^ k2) | (k0 ^ k3)) >> 21) == 0) {
      int g = (int)(k0 >> 21);
      if (g != cur) { EFLUSH(); cur = g; a0 = 0.f; a1 = 0.f; cnt = 0.f; }
      int e0 = (int)(k0 & 0x1FFFFFu), e1 = (int)(k1 & 0x1FFFFFu);
      int e2 = (int)(k2 & 0x1FFFFFu), e3 = (int)(k3 & 0x1FFFFFu);
      const float4* pA = reinterpret_cast<const float4*>(ea + (size_t)e0 * 16);
      const float4* pB = reinterpret_cast<const float4*>(ea + (size_t)e1 * 16);
      const float4* pC = reinterpret_cast<const float4*>(ea + (size_t)e2 * 16);
      const float4* pD = reinterpret_cast<const float4*>(ea + (size_t)e3 * 16);
      float4 A0 = pA[0], A1 = pA[1], A2 = pA[2], A3 = pA[3];
      float4 B0 = pB[0], B1 = pB[1], B2 = pB[2], B3 = pB[3];
      float4 C0 = pC[0], C1 = pC[1], C2 = pC[2], C3 = pC[3];
      float4 D0 = pD[0], D1 = pD[1], D2 = pD[2], D3 = pD[3];
      float uA0, uA1, uB0, uB1, uC0, uC1, uD0, uD1;
      MLP16(A0, A1, A2, A3, uA0, uA1);
      MLP16(B0, B1, B2, B3, uB0, uB1);
      MLP16(C0, C1, C2, C3, uC0, uC1);
      MLP16(D0, D1, D2, D3, uD0, uD1);
      a0 += fmaxf(uA0, 0.f) + fmaxf(uB0, 0.f) + fmaxf(uC0, 0.f) + fmaxf(uD0, 0.f);
      a1 += fmaxf(uA1, 0.f) + fmaxf(uB1, 0.f) + fmaxf(uC1, 0.f) + fmaxf(uD1, 0.f);
      cnt += 4.f;
      j += 4;
    } else {
      ONE_EDGE(k0);
      j += 1;
    }
  }
  while (j < end) {
    unsigned int k0 = epk[j];
    ONE_EDGE(k0);
    j += 1;
  }
  EFLUSH();
}

// ---------------- final: graph_repr + edge_repr ----------------
__global__ __launch_bounds__(128) void final_kernel(const float* __restrict__ gsum,
                                                    const float* __restrict__ gcnt,
                                                    const float* __restrict__ esum,
                                                    const float* __restrict__ ecnt,
                                                    const float* __restrict__ We2,
                                                    const float* __restrict__ be2,
                                                    float* __restrict__ out) {
  __shared__ float row[128];
  int g = blockIdx.x, c = threadIdx.x;
  row[c] = esum[g * 128 + c];
  __syncthreads();
  float acc = 0.f;
#pragma unroll 4
  for (int k = 0; k < 128; ++k) acc = fmaf(row[k], We2[k * 128 + c], acc);
  float ce = ecnt[g];
  float er = (ce > 0.f) ? (acc / ce + be2[c]) : 0.f;
  float cn = gcnt[g];
  float gr = gsum[g * 128 + c] / fmaxf(cn, 1.f);
  out[g * 128 + c] = gr + er;
}

extern "C" void kernel_launch(void* const* d_in, const int* in_sizes, int n_in,
                              void* d_out, int out_size, void* d_ws, size_t ws_size,
                              hipStream_t stream) {
  const float* x    = (const float*)d_in[0];
  const int*   ei   = (const int*)d_in[1];
  const float* ea   = (const float*)d_in[2];
  const int*   bidx = (const int*)d_in[3];
  const float* Wg1  = (const float*)d_in[4];
  const float* bg1  = (const float*)d_in[5];
  const float* gm1  = (const float*)d_in[6];
  const float* bt1  = (const float*)d_in[7];
  const float* Wg2  = (const float*)d_in[8];
  const float* bg2  = (const float*)d_in[9];
  const float* gm2  = (const float*)d_in[10];
  const float* bt2  = (const float*)d_in[11];
  const float* We1  = (const float*)d_in[12];
  const float* be1  = (const float*)d_in[13];
  const float* We2  = (const float*)d_in[14];
  const float* be2  = (const float*)d_in[15];
  float* out = (float*)d_out;

  const int N = in_sizes[3];
  const int E = in_sizes[1] / 2;
  const int G = out_size / 128;
  const int* srcp = ei;
  const int* dstp = ei + E;
  const int Epad = E + 8 * N;

  char* w = (char*)d_ws;
  auto alloc = [&](size_t b) {
    char* p = w;
    w += (b + 15) & ~(size_t)15;
    return p;
  };
  float* bufB    = (float*)alloc((size_t)N * 128 * 4);            // fp32 spmm output
  unsigned int* hpk2 = (unsigned int*)alloc((size_t)N * 64 * 4);  // packed bf16 h, slice-major
  int2*  swv     = (int2*)alloc((size_t)Epad * 8);                // interleaved {src, wgt}
  unsigned int* epk = (unsigned int*)alloc((size_t)E * 4);
  int*   rp      = (int*)alloc((size_t)(N + 1) * 4);
  int*   rp2     = (int*)alloc((size_t)(N + 1) * 4);
  int*   cursor  = (int*)alloc((size_t)N * 4);
  int*   cursor2 = (int*)alloc((size_t)N * 4);
  float* dinv    = (float*)alloc((size_t)N * 4);
  char* zbase = w;
  int*   deg  = (int*)alloc((size_t)N * 4);
  int*   deg2 = (int*)alloc((size_t)N * 4);
  float* bs1  = (float*)alloc(512);
  float* bq1  = (float*)alloc(512);
  float* bs2  = (float*)alloc(512);
  float* bq2  = (float*)alloc(512);
  float* gsum = (float*)alloc((size_t)G * 128 * 4);
  float* gcnt = (float*)alloc((size_t)G * 4);
  float* esum = (float*)alloc((size_t)G * 128 * 4);
  float* ecnt = (float*)alloc((size_t)G * 4);
  int*   part  = (int*)alloc(4096);
  int*   part2 = (int*)alloc(4096);
  size_t zbytes = (size_t)(w - zbase);
  float* sc1 = (float*)alloc(512);
  float* sh1 = (float*)alloc(512);
  float* sc2 = (float*)alloc(512);
  float* sh2 = (float*)alloc(512);

  hipMemsetAsync(zbase, 0, zbytes, stream);

  (void)hipFuncSetAttribute((const void*)gemm128_kernel<false>,
                            hipFuncAttributeMaxDynamicSharedMemorySize, 73728);
  (void)hipFuncSetAttribute((const void*)gemm128_kernel<true>,
                            hipFuncAttributeMaxDynamicSharedMemorySize, 73728);

  // ---- prep ----
  pre_kernel<<<(E + 255) / 256, 256, 0, stream>>>(srcp, dstp, deg, deg2, E);
  int nb = (N + 1023) / 1024;
  scanA_kernel<<<2 * nb, 256, 0, stream>>>(deg, deg2, rp, rp2, part, part2, N, nb);
  scanB_kernel<<<2, 64, 0, stream>>>(part, part2, rp, rp2, nb, N);
  scanC_kernel<<<(2 * N + 255) / 256, 256, 0, stream>>>(rp, rp2, part, part2, cursor,
                                                        cursor2, deg, dinv, N);
  placepad_kernel<<<(E + N + 255) / 256, 256, 0, stream>>>(srcp, dstp, bidx, dinv, cursor,
                                                           cursor2, swv, epk, rp, deg, E, N);

  // layer 1
  gemm128_kernel<false><<<512, 256, 73728, stream>>>(x, Wg1, nullptr, nullptr, hpk2, N);
  spmm8_kernel<<<2048, 256, 0, stream>>>(hpk2, dinv, rp, swv, bg1, bufB, bs1, bq1, N);
  bnfin_kernel<<<1, 128, 0, stream>>>(bs1, bq1, gm1, bt1, sc1, sh1, 1.0f / (float)N);

  // layer 2 (BN1+ReLU fused into GEMM2's A staging)
  gemm128_kernel<true><<<512, 256, 73728, stream>>>(bufB, Wg2, sc1, sh1, hpk2, N);
  spmm8_kernel<<<2048, 256, 0, stream>>>(hpk2, dinv, rp, swv, bg2, bufB, bs2, bq2, N);
  bnfin_kernel<<<1, 128, 0, stream>>>(bs2, bq2, gm2, bt2, sc2, sh2, 1.0f / (float)N);

  // pooling (BN2+ReLU fused) + edge path + output
  int nwp = (2048 * 256) / 64;
  int chunkN = (N + nwp - 1) / nwp;
  pool_kernel<<<2048, 256, 0, stream>>>(bufB, bidx, sc2, sh2, gsum, gcnt, N, chunkN);
  int nwe = (2048 * 256) / 64;
  int chunkE = (E + nwe - 1) / nwe;
  edge4_kernel<<<2048, 256, 0, stream>>>(ea, epk, We1, be1, esum, ecnt, E, chunkE);
  final_kernel<<<G, 128, 0, stream>>>(gsum, gcnt, esum, ecnt, We2, be2, out);
}

// Round 11
// 1235.610 us; speedup vs baseline: 1.5937x; 1.2123x over previous
//
#include <hip/hip_runtime.h>
#include <cstdint>

// ---- bf16 pack/unpack helpers (RNE) ----
__device__ inline unsigned int bfpack2(float a, float b) {
  unsigned int ua = __float_as_uint(a), ub = __float_as_uint(b);
  ua += 0x7FFFu + ((ua >> 16) & 1u);
  ub += 0x7FFFu + ((ub >> 16) & 1u);
  return (ua >> 16) | (ub & 0xFFFF0000u);
}
__device__ inline float bflo(unsigned int u) { return __uint_as_float(u << 16); }
__device__ inline float bfhi(unsigned int u) { return __uint_as_float(u & 0xFFFF0000u); }

// ---------------- degree histograms ----------------
__global__ __launch_bounds__(256) void pre_kernel(const int* __restrict__ src,
                                                  const int* __restrict__ dst,
                                                  int* __restrict__ deg,
                                                  int* __restrict__ deg2, int nE) {
  int e = blockIdx.x * 256 + threadIdx.x;
  if (e < nE) {
    atomicAdd(&deg[dst[e]], 1);
    atomicAdd(&deg2[src[e]], 1);
  }
}

// ---------------- scan stage A (dual; deg gets 8-pad rounding) ----------------
__global__ __launch_bounds__(256) void scanA_kernel(const int* __restrict__ deg,
                                                    const int* __restrict__ deg2,
                                                    int* __restrict__ rp,
                                                    int* __restrict__ rp2,
                                                    int* __restrict__ part,
                                                    int* __restrict__ part2,
                                                    int n, int nb) {
  __shared__ int sh[256];
  int b = blockIdx.x, t = threadIdx.x;
  const int* d = (b < nb) ? deg : deg2;
  int* r = (b < nb) ? rp : rp2;
  int* p = (b < nb) ? part : part2;
  int pad = (b < nb) ? 1 : 0;
  int bb = (b < nb) ? b : b - nb;
  int base = bb * 1024 + t * 4;
  int v0 = (base + 0 < n) ? d[base + 0] : 0;
  int v1 = (base + 1 < n) ? d[base + 1] : 0;
  int v2 = (base + 2 < n) ? d[base + 2] : 0;
  int v3 = (base + 3 < n) ? d[base + 3] : 0;
  if (pad) {
    v0 = (v0 + 7) & ~7; v1 = (v1 + 7) & ~7;
    v2 = (v2 + 7) & ~7; v3 = (v3 + 7) & ~7;
  }
  int ts = v0 + v1 + v2 + v3;
  sh[t] = ts;
  __syncthreads();
  for (int off = 1; off < 256; off <<= 1) {
    int x = (t >= off) ? sh[t - off] : 0;
    __syncthreads();
    sh[t] += x;
    __syncthreads();
  }
  int excl = sh[t] - ts;
  if (t == 255) p[bb] = sh[255];
  if (base + 0 < n) r[base + 0] = excl;
  if (base + 1 < n) r[base + 1] = excl + v0;
  if (base + 2 < n) r[base + 2] = excl + v0 + v1;
  if (base + 3 < n) r[base + 3] = excl + v0 + v1 + v2;
}

__global__ void scanB_kernel(int* part, int* part2, int* rp, int* rp2, int nb, int n) {
  if (threadIdx.x == 0) {
    int* p = (blockIdx.x == 0) ? part : part2;
    int* r = (blockIdx.x == 0) ? rp : rp2;
    int run = 0;
    for (int i = 0; i < nb; ++i) { int v = p[i]; p[i] = run; run += v; }
    r[n] = run;
  }
}

__global__ __launch_bounds__(256) void scanC_kernel(int* __restrict__ rp,
                                                    int* __restrict__ rp2,
                                                    const int* __restrict__ part,
                                                    const int* __restrict__ part2,
                                                    int* __restrict__ cursor,
                                                    int* __restrict__ cursor2,
                                                    const int* __restrict__ deg,
                                                    float* __restrict__ dinv, int n) {
  int i = blockIdx.x * 256 + threadIdx.x;
  if (i < n) {
    int v = rp[i] + part[i >> 10];
    rp[i] = v;
    cursor[i] = v;
    dinv[i] = rsqrtf((float)deg[i] + 1.0f);
  } else if (i < 2 * n) {
    int j = i - n;
    int v = rp2[j] + part2[j >> 10];
    rp2[j] = v;
    cursor2[j] = v;
  }
}

// ---------------- place + pad fused (also records pos2 = graph-sort rank) ----------------
__global__ __launch_bounds__(256) void placepad_kernel(const int* __restrict__ src,
                                                       const int* __restrict__ dst,
                                                       const int* __restrict__ batch,
                                                       const float* __restrict__ dinv,
                                                       int* __restrict__ cursor,
                                                       int* __restrict__ cursor2,
                                                       int2* __restrict__ swv,
                                                       unsigned int* __restrict__ epk,
                                                       int* __restrict__ pos2,
                                                       const int* __restrict__ rp,
                                                       const int* __restrict__ deg,
                                                       int nE, int nN) {
  int t = blockIdx.x * 256 + threadIdx.x;
  if (t < nE) {
    int s = src[t];
    int d = dst[t];
    int p1 = atomicAdd(&cursor[d], 1);
    int2 sw; sw.x = s; sw.y = __float_as_int(dinv[s] * dinv[d]);
    swv[p1] = sw;
    int g = batch[s];
    int p2 = atomicAdd(&cursor2[s], 1);
    epk[p2] = ((unsigned int)g << 21) | (unsigned int)t;
    pos2[t] = p2;
  } else if (t < nE + nN) {
    int i = t - nE;
    int b = rp[i] + deg[i], e = rp[i + 1];
    int2 z; z.x = i; z.y = 0;
    for (int k = b; k < e; ++k) swv[k] = z;
  }
}

// ---------------- dense GEMM: hpk2[8][N][8] = pack_bf16(act(A) @ W), slice-major ----------------
template <bool FUSED>
__global__ __launch_bounds__(256) void gemm128_kernel(const float* __restrict__ A,
                                                      const float* __restrict__ W,
                                                      const float* __restrict__ scale,
                                                      const float* __restrict__ shift,
                                                      unsigned int* __restrict__ hpk2,
                                                      int nrows) {
  extern __shared__ float lds[];
  float* Ws = lds;
  float* xs = lds + 128 * 128;
  const int t = threadIdx.x;
  for (int i = t; i < (128 * 128) / 4; i += 256)
    reinterpret_cast<float4*>(Ws)[i] = reinterpret_cast<const float4*>(W)[i];
  const int wave = t >> 6, lane = t & 63;
  const size_t sbase = (size_t)(lane >> 3) * (size_t)nrows * 8 + (lane & 7);
  for (int rb = blockIdx.x * 16; rb < nrows; rb += gridDim.x * 16) {
    int nr = min(16, nrows - rb);
    __syncthreads();
    for (int i = t; i < nr * 32; i += 256) {
      float4 v = reinterpret_cast<const float4*>(A + (size_t)rb * 128)[i];
      if (FUSED) {
        float4 sc4 = reinterpret_cast<const float4*>(scale)[i & 31];
        float4 sh4 = reinterpret_cast<const float4*>(shift)[i & 31];
        v.x = fmaxf(fmaf(v.x, sc4.x, sh4.x), 0.f);
        v.y = fmaxf(fmaf(v.y, sc4.y, sh4.y), 0.f);
        v.z = fmaxf(fmaf(v.z, sc4.z, sh4.z), 0.f);
        v.w = fmaxf(fmaf(v.w, sc4.w, sh4.w), 0.f);
      }
      reinterpret_cast<float4*>(xs)[i] = v;
    }
    __syncthreads();
    float acc[4][2] = {{0.f, 0.f}, {0.f, 0.f}, {0.f, 0.f}, {0.f, 0.f}};
    const float* xw = xs + wave * 4 * 128;
#pragma unroll 4
    for (int k = 0; k < 128; ++k) {
      float w0 = Ws[k * 128 + lane];
      float w1 = Ws[k * 128 + 64 + lane];
#pragma unroll
      for (int r = 0; r < 4; ++r) {
        float a = xw[r * 128 + k];
        acc[r][0] = fmaf(a, w0, acc[r][0]);
        acc[r][1] = fmaf(a, w1, acc[r][1]);
      }
    }
#pragma unroll
    for (int r = 0; r < 4; ++r) {
      int row = rb + wave * 4 + r;
      if (row < nrows)
        hpk2[sbase + (size_t)row * 8] = bfpack2(acc[r][0], acc[r][1]);
    }
  }
}

// ---------------- SpMM, XCD channel-sliced, TWO nodes per wave ----------------
__global__ __launch_bounds__(256) void spmm8_kernel(const unsigned int* __restrict__ hpk2,
                                                    const float* __restrict__ dinv,
                                                    const int* __restrict__ rp,
                                                    const int2* __restrict__ swv,
                                                    const float* __restrict__ bias,
                                                    float* __restrict__ outp,
                                                    float* __restrict__ bnsum,
                                                    float* __restrict__ bnsq, int nN) {
  const int lane = threadIdx.x & 63;
  const int ch = lane & 7;
  const int es = lane >> 3;
  const int slice = blockIdx.x & 7;
  const unsigned int* hs = hpk2 + (size_t)slice * (size_t)nN * 8;
  const int cb = slice * 8;
  const int wib = (int)(blockIdx.x >> 3) * 4 + (int)(threadIdx.x >> 6);
  const int nws = (int)(gridDim.x >> 3) * 4;
  const unsigned long long* swq = reinterpret_cast<const unsigned long long*>(swv);
  float b0 = bias[cb + ch], b1 = bias[64 + cb + ch];
  float s0 = 0.f, s1 = 0.f, q0 = 0.f, q1 = 0.f;
  const int half = (nN + 1) >> 1;

#define SPMM_CHUNK(J, ACC0, ACC1)                                         \
  {                                                                       \
    unsigned long long v_ = __builtin_nontemporal_load(swq + (J) + es);   \
    unsigned int pp_ = hs[(size_t)(unsigned int)v_ * 8 + ch];             \
    float ww_ = __uint_as_float((unsigned int)(v_ >> 32));                \
    ACC0 = fmaf(ww_, bflo(pp_), ACC0);                                    \
    ACC1 = fmaf(ww_, bfhi(pp_), ACC1);                                    \
  }

  for (int p = wib; p < half; p += nws) {
    const int n0 = p;
    const int n1 = p + half;
    const bool has1 = n1 < nN;
    int j0 = rp[n0];
    const int end0 = rp[n0 + 1];
    int j1 = 0, end1 = 0;
    if (has1) { j1 = rp[n1]; end1 = rp[n1 + 1]; }
    float a00 = 0.f, a01 = 0.f, b00 = 0.f, b01 = 0.f;
    float a10 = 0.f, a11 = 0.f, b10 = 0.f, b11 = 0.f;
    while (j0 + 8 < end0 && j1 + 8 < end1) {
      SPMM_CHUNK(j0, a00, a01);
      SPMM_CHUNK(j0 + 8, b00, b01);
      SPMM_CHUNK(j1, a10, a11);
      SPMM_CHUNK(j1 + 8, b10, b11);
      j0 += 16; j1 += 16;
    }
    while (j0 + 8 < end0) {
      SPMM_CHUNK(j0, a00, a01);
      SPMM_CHUNK(j0 + 8, b00, b01);
      j0 += 16;
    }
    if (j0 < end0) SPMM_CHUNK(j0, a00, a01);
    while (j1 + 8 < end1) {
      SPMM_CHUNK(j1, a10, a11);
      SPMM_CHUNK(j1 + 8, b10, b11);
      j1 += 16;
    }
    if (j1 < end1) SPMM_CHUNK(j1, a10, a11);

    a00 += b00; a01 += b01;
    a10 += b10; a11 += b11;
    a00 += __shfl_xor(a00, 8);  a01 += __shfl_xor(a01, 8);
    a10 += __shfl_xor(a10, 8);  a11 += __shfl_xor(a11, 8);
    a00 += __shfl_xor(a00, 16); a01 += __shfl_xor(a01, 16);
    a10 += __shfl_xor(a10, 16); a11 += __shfl_xor(a11, 16);
    a00 += __shfl_xor(a00, 32); a01 += __shfl_xor(a01, 32);
    a10 += __shfl_xor(a10, 32); a11 += __shfl_xor(a11, 32);
    if (es == 0) {
      {
        float dn = dinv[n0];
        float sw = dn * dn;
        unsigned int pn = hs[(size_t)n0 * 8 + ch];
        float o0 = fmaf(bflo(pn), sw, a00) + b0;
        float o1 = fmaf(bfhi(pn), sw, a01) + b1;
        __builtin_nontemporal_store(o0, &outp[(size_t)n0 * 128 + cb + ch]);
        __builtin_nontemporal_store(o1, &outp[(size_t)n0 * 128 + 64 + cb + ch]);
        s0 += o0; s1 += o1;
        q0 = fmaf(o0, o0, q0); q1 = fmaf(o1, o1, q1);
      }
      if (has1) {
        float dn = dinv[n1];
        float sw = dn * dn;
        unsigned int pn = hs[(size_t)n1 * 8 + ch];
        float o0 = fmaf(bflo(pn), sw, a10) + b0;
        float o1 = fmaf(bfhi(pn), sw, a11) + b1;
        __builtin_nontemporal_store(o0, &outp[(size_t)n1 * 128 + cb + ch]);
        __builtin_nontemporal_store(o1, &outp[(size_t)n1 * 128 + 64 + cb + ch]);
        s0 += o0; s1 += o1;
        q0 = fmaf(o0, o0, q0); q1 = fmaf(o1, o1, q1);
      }
    }
  }
#undef SPMM_CHUNK
  if (es == 0) {
    atomicAdd(&bnsum[cb + ch], s0);
    atomicAdd(&bnsum[64 + cb + ch], s1);
    atomicAdd(&bnsq[cb + ch], q0);
    atomicAdd(&bnsq[64 + cb + ch], q1);
  }
}

// ---------------- BN finalize ----------------
__global__ void bnfin_kernel(const float* __restrict__ sum, const float* __restrict__ sq,
                             const float* __restrict__ gamma, const float* __restrict__ beta,
                             float* __restrict__ scale, float* __restrict__ shift,
                             float invN) {
  int c = threadIdx.x;
  float mu = sum[c] * invN;
  float var = sq[c] * invN - mu * mu;
  float sc = gamma[c] * rsqrtf(var + 1e-5f);
  scale[c] = sc;
  shift[c] = beta[c] - mu * sc;
}

// ---------------- graph mean pool, fused BN+ReLU ----------------
__global__ __launch_bounds__(256) void pool_kernel(const float* __restrict__ h,
                                                   const int* __restrict__ batch,
                                                   const float* __restrict__ scale,
                                                   const float* __restrict__ shift,
                                                   float* __restrict__ gsum,
                                                   float* __restrict__ gcnt,
                                                   int nN, int chunk) {
  const int lane = threadIdx.x & 63;
  const int wid = (blockIdx.x * blockDim.x + threadIdx.x) >> 6;
  int beg = wid * chunk;
  if (beg >= nN) return;
  int end = min(nN, beg + chunk);
  const int c2 = 2 * lane;
  float2 sc2 = *reinterpret_cast<const float2*>(scale + c2);
  float2 sh2 = *reinterpret_cast<const float2*>(shift + c2);
  int cur = -1;
  float a0 = 0.f, a1 = 0.f, cnt = 0.f;
  for (int n = beg; n < end; ++n) {
    int g = batch[n];
    if (g != cur) {
      if (cur >= 0) {
        atomicAdd(&gsum[cur * 128 + c2], a0);
        atomicAdd(&gsum[cur * 128 + c2 + 1], a1);
        if (lane == 0) atomicAdd(&gcnt[cur], cnt);
      }
      cur = g; a0 = 0.f; a1 = 0.f; cnt = 0.f;
    }
    float2 v = *reinterpret_cast<const float2*>(h + (size_t)n * 128 + c2);
    a0 += fmaxf(fmaf(v.x, sc2.x, sh2.x), 0.f);
    a1 += fmaxf(fmaf(v.y, sc2.y, sh2.y), 0.f);
    cnt += 1.f;
  }
  if (cur >= 0) {
    atomicAdd(&gsum[cur * 128 + c2], a0);
    atomicAdd(&gsum[cur * 128 + c2 + 1], a1);
    if (lane == 0) atomicAdd(&gcnt[cur], cnt);
  }
}

// ---------------- ea reorder: sequential read, bf16 pack, scatter to graph order ----------------
// Reads ea coalesced (64B/thread), writes 32B bf16 row at graph-sorted position.
// Writes are posted; target (51.2 MB) is L2/L3-absorbable and aliases dead bufB.
__global__ __launch_bounds__(256) void scatter_kernel(const float* __restrict__ ea,
                                                      const int* __restrict__ pos2,
                                                      unsigned int* __restrict__ eah, int nE) {
  int e = blockIdx.x * 256 + threadIdx.x;
  if (e < nE) {
    const float4* p = reinterpret_cast<const float4*>(ea + (size_t)e * 16);
    float4 a = p[0], b = p[1], c = p[2], d = p[3];
    uint4 o0, o1;
    o0.x = bfpack2(a.x, a.y); o0.y = bfpack2(a.z, a.w);
    o0.z = bfpack2(b.x, b.y); o0.w = bfpack2(b.z, b.w);
    o1.x = bfpack2(c.x, c.y); o1.y = bfpack2(c.z, c.w);
    o1.z = bfpack2(d.x, d.y); o1.w = bfpack2(d.z, d.w);
    int j = pos2[e];
    uint4* dst = reinterpret_cast<uint4*>(eah + (size_t)j * 8);
    dst[0] = o0;
    dst[1] = o1;
  }
}

// ---------------- edge MLP: STREAM graph-sorted bf16 rows, run-length regs ----------------
__global__ __launch_bounds__(256) void edge6_kernel(const unsigned int* __restrict__ eah,
                                                    const unsigned int* __restrict__ epk,
                                                    const float* __restrict__ We1,
                                                    const float* __restrict__ be1,
                                                    float* __restrict__ esum,
                                                    float* __restrict__ ecnt,
                                                    int nE, int chunk) {
  const int lane = threadIdx.x & 63;
  const int wid = (blockIdx.x * 256 + threadIdx.x) >> 6;
  int beg = wid * chunk;
  if (beg >= nE) return;
  int end = min(nE, beg + chunk);
  float w0[16], w1[16];
#pragma unroll
  for (int k = 0; k < 16; ++k) {
    w0[k] = We1[k * 128 + lane];
    w1[k] = We1[k * 128 + 64 + lane];
  }
  float b0 = be1[lane], b1 = be1[64 + lane];
  int cur = -1;
  float a0 = 0.f, a1 = 0.f, cnt = 0.f;
  // software pipeline: preload row j while computing row j-1
  const uint4* rowp = reinterpret_cast<const uint4*>(eah + (size_t)beg * 8);
  uint4 q0 = rowp[0], q1 = rowp[1];
  int g = (int)(epk[beg] >> 21);
  for (int j = beg; j < end; ++j) {
    uint4 n0, n1;
    int ng = g;
    if (j + 1 < end) {
      const uint4* np = reinterpret_cast<const uint4*>(eah + (size_t)(j + 1) * 8);
      n0 = np[0];
      n1 = np[1];
      ng = (int)(epk[j + 1] >> 21);
    }
    if (g != cur) {
      if (cur >= 0) {
        atomicAdd(&esum[cur * 128 + lane], a0);
        atomicAdd(&esum[cur * 128 + 64 + lane], a1);
        if (lane == 0) atomicAdd(&ecnt[cur], cnt);
      }
      cur = g; a0 = 0.f; a1 = 0.f; cnt = 0.f;
    }
    float u0 = b0, u1 = b1;
    float f;
    f = bflo(q0.x); u0 = fmaf(f, w0[0], u0);  u1 = fmaf(f, w1[0], u1);
    f = bfhi(q0.x); u0 = fmaf(f, w0[1], u0);  u1 = fmaf(f, w1[1], u1);
    f = bflo(q0.y); u0 = fmaf(f, w0[2], u0);  u1 = fmaf(f, w1[2], u1);
    f = bfhi(q0.y); u0 = fmaf(f, w0[3], u0);  u1 = fmaf(f, w1[3], u1);
    f = bflo(q0.z); u0 = fmaf(f, w0[4], u0);  u1 = fmaf(f, w1[4], u1);
    f = bfhi(q0.z); u0 = fmaf(f, w0[5], u0);  u1 = fmaf(f, w1[5], u1);
    f = bflo(q0.w); u0 = fmaf(f, w0[6], u0);  u1 = fmaf(f, w1[6], u1);
    f = bfhi(q0.w); u0 = fmaf(f, w0[7], u0);  u1 = fmaf(f, w1[7], u1);
    f = bflo(q1.x); u0 = fmaf(f, w0[8], u0);  u1 = fmaf(f, w1[8], u1);
    f = bfhi(q1.x); u0 = fmaf(f, w0[9], u0);  u1 = fmaf(f, w1[9], u1);
    f = bflo(q1.y); u0 = fmaf(f, w0[10], u0); u1 = fmaf(f, w1[10], u1);
    f = bfhi(q1.y); u0 = fmaf(f, w0[11], u0); u1 = fmaf(f, w1[11], u1);
    f = bflo(q1.z); u0 = fmaf(f, w0[12], u0); u1 = fmaf(f, w1[12], u1);
    f = bfhi(q1.z); u0 = fmaf(f, w0[13], u0); u1 = fmaf(f, w1[13], u1);
    f = bflo(q1.w); u0 = fmaf(f, w0[14], u0); u1 = fmaf(f, w1[14], u1);
    f = bfhi(q1.w); u0 = fmaf(f, w0[15], u0); u1 = fmaf(f, w1[15], u1);
    a0 += fmaxf(u0, 0.f);
    a1 += fmaxf(u1, 0.f);
    cnt += 1.f;
    q0 = n0; q1 = n1; g = ng;
  }
  if (cur >= 0) {
    atomicAdd(&esum[cur * 128 + lane], a0);
    atomicAdd(&esum[cur * 128 + 64 + lane], a1);
    if (lane == 0) atomicAdd(&ecnt[cur], cnt);
  }
}

// ---------------- final: graph_repr + edge_repr ----------------
__global__ __launch_bounds__(128) void final_kernel(const float* __restrict__ gsum,
                                                    const float* __restrict__ gcnt,
                                                    const float* __restrict__ esum,
                                                    const float* __restrict__ ecnt,
                                                    const float* __restrict__ We2,
                                                    const float* __restrict__ be2,
                                                    float* __restrict__ out) {
  __shared__ float row[128];
  int g = blockIdx.x, c = threadIdx.x;
  row[c] = esum[g * 128 + c];
  __syncthreads();
  float acc = 0.f;
#pragma unroll 4
  for (int k = 0; k < 128; ++k) acc = fmaf(row[k], We2[k * 128 + c], acc);
  float ce = ecnt[g];
  float er = (ce > 0.f) ? (acc / ce + be2[c]) : 0.f;
  float cn = gcnt[g];
  float gr = gsum[g * 128 + c] / fmaxf(cn, 1.f);
  out[g * 128 + c] = gr + er;
}

extern "C" void kernel_launch(void* const* d_in, const int* in_sizes, int n_in,
                              void* d_out, int out_size, void* d_ws, size_t ws_size,
                              hipStream_t stream) {
  const float* x    = (const float*)d_in[0];
  const int*   ei   = (const int*)d_in[1];
  const float* ea   = (const float*)d_in[2];
  const int*   bidx = (const int*)d_in[3];
  const float* Wg1  = (const float*)d_in[4];
  const float* bg1  = (const float*)d_in[5];
  const float* gm1  = (const float*)d_in[6];
  const float* bt1  = (const float*)d_in[7];
  const float* Wg2  = (const float*)d_in[8];
  const float* bg2  = (const float*)d_in[9];
  const float* gm2  = (const float*)d_in[10];
  const float* bt2  = (const float*)d_in[11];
  const float* We1  = (const float*)d_in[12];
  const float* be1  = (const float*)d_in[13];
  const float* We2  = (const float*)d_in[14];
  const float* be2  = (const float*)d_in[15];
  float* out = (float*)d_out;

  const int N = in_sizes[3];
  const int E = in_sizes[1] / 2;
  const int G = out_size / 128;
  const int* srcp = ei;
  const int* dstp = ei + E;
  const int Epad = E + 8 * N;

  char* w = (char*)d_ws;
  auto alloc = [&](size_t b) {
    char* p = w;
    w += (b + 15) & ~(size_t)15;
    return p;
  };
  float* bufB    = (float*)alloc((size_t)N * 128 * 4);            // fp32 spmm output; dead after pool
  unsigned int* hpk2 = (unsigned int*)alloc((size_t)N * 64 * 4);  // packed bf16 h, slice-major
  int2*  swv     = (int2*)alloc((size_t)Epad * 8);                // interleaved {src, wgt}
  unsigned int* epk = (unsigned int*)alloc((size_t)E * 4);
  int*   pos2    = (int*)alloc((size_t)E * 4);                    // graph-sort rank per edge
  int*   rp      = (int*)alloc((size_t)(N + 1) * 4);
  int*   rp2     = (int*)alloc((size_t)(N + 1) * 4);
  int*   cursor  = (int*)alloc((size_t)N * 4);
  int*   cursor2 = (int*)alloc((size_t)N * 4);
  float* dinv    = (float*)alloc((size_t)N * 4);
  char* zbase = w;
  int*   deg  = (int*)alloc((size_t)N * 4);
  int*   deg2 = (int*)alloc((size_t)N * 4);
  float* bs1  = (float*)alloc(512);
  float* bq1  = (float*)alloc(512);
  float* bs2  = (float*)alloc(512);
  float* bq2  = (float*)alloc(512);
  float* gsum = (float*)alloc((size_t)G * 128 * 4);
  float* gcnt = (float*)alloc((size_t)G * 4);
  float* esum = (float*)alloc((size_t)G * 128 * 4);
  float* ecnt = (float*)alloc((size_t)G * 4);
  int*   part  = (int*)alloc(4096);
  int*   part2 = (int*)alloc(4096);
  size_t zbytes = (size_t)(w - zbase);
  float* sc1 = (float*)alloc(512);
  float* sh1 = (float*)alloc(512);
  float* sc2 = (float*)alloc(512);
  float* sh2 = (float*)alloc(512);

  // eah (E x 32B bf16 rows, graph-sorted) aliases bufB (both 51.2 MB); bufB is
  // dead after pool_kernel, and scatter/edge6 run after it.
  unsigned int* eah = (unsigned int*)bufB;

  hipMemsetAsync(zbase, 0, zbytes, stream);

  (void)hipFuncSetAttribute((const void*)gemm128_kernel<false>,
                            hipFuncAttributeMaxDynamicSharedMemorySize, 73728);
  (void)hipFuncSetAttribute((const void*)gemm128_kernel<true>,
                            hipFuncAttributeMaxDynamicSharedMemorySize, 73728);

  // ---- prep ----
  pre_kernel<<<(E + 255) / 256, 256, 0, stream>>>(srcp, dstp, deg, deg2, E);
  int nb = (N + 1023) / 1024;
  scanA_kernel<<<2 * nb, 256, 0, stream>>>(deg, deg2, rp, rp2, part, part2, N, nb);
  scanB_kernel<<<2, 64, 0, stream>>>(part, part2, rp, rp2, nb, N);
  scanC_kernel<<<(2 * N + 255) / 256, 256, 0, stream>>>(rp, rp2, part, part2, cursor,
                                                        cursor2, deg, dinv, N);
  placepad_kernel<<<(E + N + 255) / 256, 256, 0, stream>>>(srcp, dstp, bidx, dinv, cursor,
                                                           cursor2, swv, epk, pos2, rp, deg,
                                                           E, N);

  // layer 1
  gemm128_kernel<false><<<512, 256, 73728, stream>>>(x, Wg1, nullptr, nullptr, hpk2, N);
  spmm8_kernel<<<2048, 256, 0, stream>>>(hpk2, dinv, rp, swv, bg1, bufB, bs1, bq1, N);
  bnfin_kernel<<<1, 128, 0, stream>>>(bs1, bq1, gm1, bt1, sc1, sh1, 1.0f / (float)N);

  // layer 2 (BN1+ReLU fused into GEMM2's A staging)
  gemm128_kernel<true><<<512, 256, 73728, stream>>>(bufB, Wg2, sc1, sh1, hpk2, N);
  spmm8_kernel<<<2048, 256, 0, stream>>>(hpk2, dinv, rp, swv, bg2, bufB, bs2, bq2, N);
  bnfin_kernel<<<1, 128, 0, stream>>>(bs2, bq2, gm2, bt2, sc2, sh2, 1.0f / (float)N);

  // pooling (BN2+ReLU fused) -- last reader of bufB
  int nwp = (2048 * 256) / 64;
  int chunkN = (N + nwp - 1) / nwp;
  pool_kernel<<<2048, 256, 0, stream>>>(bufB, bidx, sc2, sh2, gsum, gcnt, N, chunkN);

  // edge path: reorder ea into graph order (bf16) then stream
  scatter_kernel<<<(E + 255) / 256, 256, 0, stream>>>(ea, pos2, eah, E);
  int nwe = (2048 * 256) / 64;
  int chunkE = (E + nwe - 1) / nwe;
  edge6_kernel<<<2048, 256, 0, stream>>>(eah, epk, We1, be1, esum, ecnt, E, chunkE);

  final_kernel<<<G, 128, 0, stream>>>(gsum, gcnt, esum, ecnt, We2, be2, out);
}